// Round 6
// baseline (17797.511 us; speedup 1.0000x reference)
//
#include <hip/hip_runtime.h>
#include <hip/hip_bf16.h>
#include <cstdint>
#include <cstddef>

typedef short bf16x8 __attribute__((ext_vector_type(8)));
typedef float f32x4  __attribute__((ext_vector_type(4)));
typedef unsigned int u32x4 __attribute__((ext_vector_type(4)));
typedef __hip_bfloat16 bf16;

#define NT_T 512
#define NB   64
#define NI   512
#define NH   1024
#define NO   512

// h history slots: 64x1024 bf16 + 128-element pad (slot-aligned, no line straddle)
static constexpr size_t SLOT_E = (size_t)NB * NH + 128;
static constexpr size_t SLOT_B = SLOT_E * 2;

// ---------------- workspace layout (bytes, all 256-aligned) ----------------
static constexpr size_t OFF_XBF   = 0;
static constexpr size_t SZ_XBF    = (size_t)NT_T * NB * NI * 2;
static constexpr size_t OFF_WSW0  = OFF_XBF + SZ_XBF;
static constexpr size_t SZ_WSW0   = 128ull * 98304;
static constexpr size_t OFF_WSW1  = OFF_WSW0 + SZ_WSW0;
static constexpr size_t SZ_WSW1   = 128ull * 131072;
static constexpr size_t OFF_WOUT  = OFF_WSW1 + SZ_WSW1;
static constexpr size_t SZ_WOUT   = (size_t)NO * NH * 2;
static constexpr size_t OFF_B0    = OFF_WOUT + SZ_WOUT;
static constexpr size_t OFF_B1    = OFF_B0 + 4096 * 4;
static constexpr size_t OFF_H1    = OFF_B1 + 4096 * 4;
static constexpr size_t SZ_H1     = (size_t)NT_T * SLOT_B;
static constexpr size_t OFF_H2    = OFF_H1 + SZ_H1;
static constexpr size_t SZ_H2     = (size_t)NT_T * SLOT_B;
// total ~198.4 MB. NO flag region: h data is its own readiness signal.
// Sentinel 0xFFFFFFFF (two bf16 NaNs) pre-fills h1/h2; the LSTM cell output
// h = sigm(o)*tanh(c) is always finite -> never writes the sentinel.

__device__ __forceinline__ float sigm(float x) {
  return 1.0f / (1.0f + __expf(-x));
}
__device__ __forceinline__ float tanh_fast(float x) {
  x = fminf(15.0f, fmaxf(-15.0f, x));
  const float e = __expf(2.0f * x);
  return (e - 1.0f) / (e + 1.0f);
}

// ---- data-is-the-flag poll loader ----
// Loads N k-slices (2 row-fragments each, 16B per fragment) with relaxed
// AGENT-scope u32 loads (bypass possibly-stale per-XCD L2 -> served from the
// coherence point). Re-sweeps until no lane sees the sentinel. Each 16B
// fragment is exactly one producer block's 16B-aligned column slice, so a
// sentinel-free fragment == that producer's step data has arrived. Loads are
// compiler-managed (correctness-safe vs. round-5's asm NaN failure); the
// sweep structure tolerates partial batching.
template <int N>
__device__ __forceinline__ void poll_tile(bf16x8 (&A)[N][2], const bf16* p0, const bf16* p1) {
  const unsigned int* q0 = (const unsigned int*)p0;
  const unsigned int* q1 = (const unsigned int*)p1;
  unsigned int V[N][2][4];
  while (true) {
#pragma unroll
    for (int i = 0; i < N; ++i)
#pragma unroll
      for (int j = 0; j < 4; ++j) {
        V[i][0][j] = __hip_atomic_load(q0 + i * 16 + j, __ATOMIC_RELAXED, __HIP_MEMORY_SCOPE_AGENT);
        V[i][1][j] = __hip_atomic_load(q1 + i * 16 + j, __ATOMIC_RELAXED, __HIP_MEMORY_SCOPE_AGENT);
      }
    bool ok = true;
#pragma unroll
    for (int i = 0; i < N; ++i)
#pragma unroll
      for (int r = 0; r < 2; ++r)
#pragma unroll
        for (int j = 0; j < 4; ++j)
          ok &= (V[i][r][j] != 0xFFFFFFFFu);
    if (__all(ok)) break;
    __builtin_amdgcn_s_sleep(1);
  }
#pragma unroll
  for (int i = 0; i < N; ++i)
#pragma unroll
    for (int r = 0; r < 2; ++r) {
      const u32x4 tv = {V[i][r][0], V[i][r][1], V[i][r][2], V[i][r][3]};
      A[i][r] = __builtin_bit_cast(bf16x8, tv);
    }
  asm volatile("" ::: "memory");
}

// plain batch load (x path: static data, plain cached loads)
template <int N>
__device__ __forceinline__ void load_batch(bf16x8 (&A)[N][2], const bf16* p0, const bf16* p1) {
#pragma unroll
  for (int i = 0; i < N; ++i) {
    A[i][0] = *(const bf16x8*)(p0 + i * 32);
    A[i][1] = *(const bf16x8*)(p1 + i * 32);
  }
}

template <int N, int KSW>
__device__ __forceinline__ void mfma_batch(f32x4 (&acc)[2][2], const bf16x8 (&A)[N][2],
                                           const char* Wlds, int ksbase, int lane) {
#pragma unroll
  for (int i = 0; i < N; ++i) {
#pragma unroll
    for (int nt = 0; nt < 2; ++nt) {
      const bf16x8 b = *(const bf16x8*)(Wlds + ((size_t)(nt * KSW + ksbase + i) * 64 + lane) * 16);
      acc[0][nt] = __builtin_amdgcn_mfma_f32_16x16x32_bf16(A[i][0], b, acc[0][nt], 0, 0, 0);
      acc[1][nt] = __builtin_amdgcn_mfma_f32_16x16x32_bf16(A[i][1], b, acc[1][nt], 0, 0, 0);
    }
  }
}

// ---------------- prep kernels ----------------
__global__ void k_convert_x(const float* __restrict__ x, bf16* __restrict__ xbf) {
  const size_t n = (size_t)NT_T * NB * NI;
  for (size_t i = (size_t)blockIdx.x * blockDim.x + threadIdx.x; i < n;
       i += (size_t)gridDim.x * blockDim.x)
    xbf[i] = __float2bfloat16(x[i]);
}

// sentinel-fill the h history region (plain stores; kernel-end release writes
// them back to the coherence point before lstm_recur's agent-scope polls)
__global__ void k_fill(u32x4* __restrict__ p, size_t n16) {
  const u32x4 s = {0xFFFFFFFFu, 0xFFFFFFFFu, 0xFFFFFFFFu, 0xFFFFFFFFu};
  for (size_t i = (size_t)blockIdx.x * blockDim.x + threadIdx.x; i < n16;
       i += (size_t)gridDim.x * blockDim.x)
    p[i] = s;
}

// Per-block, per-lane fragment-ordered weight images.
// B-fragment of mfma_f32_16x16x32_bf16: lane l holds B[n = l&15][k = (l>>4)*8 + j].
// Layout: [blk][nt(2)][ks][lane(64)][j(8)]; K-concat: L0 [W_ih0|W_hh0] ks 0..47,
// L1 [W_ih1|W_hh1] ks 0..63. Gate rows per block: [i f g o] x 8 cols at blk*8.
__global__ void k_build_wsw(const float* __restrict__ Wih0, const float* __restrict__ Whh0,
                            const float* __restrict__ Wih1, const float* __restrict__ Whh1,
                            bf16* __restrict__ wsw0, bf16* __restrict__ wsw1) {
  const size_t L0N = 128ull * 2 * 48 * 64 * 8;
  const size_t L1N = 128ull * 2 * 64 * 64 * 8;
  const size_t n = L0N + L1N;
  for (size_t i = (size_t)blockIdx.x * blockDim.x + threadIdx.x; i < n;
       i += (size_t)gridDim.x * blockDim.x) {
    if (i < L0N) {
      size_t idx = i;
      const int j = idx & 7;    idx >>= 3;
      const int lane = idx & 63; idx >>= 6;
      const int ks = (int)(idx % 48); idx /= 48;
      const int nt = idx & 1;
      const int blk = (int)(idx >> 1);
      const int nl = nt * 16 + (lane & 15);
      const int k = ks * 32 + (lane >> 4) * 8 + j;
      const int grow = (nl >> 3) * 1024 + blk * 8 + (nl & 7);
      const float v = (k < 512) ? Wih0[(size_t)grow * 512 + k]
                                : Whh0[(size_t)grow * 1024 + (k - 512)];
      wsw0[i] = __float2bfloat16(v);
    } else {
      size_t idx = i - L0N;
      const size_t o = idx;
      const int j = idx & 7;    idx >>= 3;
      const int lane = idx & 63; idx >>= 6;
      const int ks = (int)(idx % 64); idx /= 64;
      const int nt = idx & 1;
      const int blk = (int)(idx >> 1);
      const int nl = nt * 16 + (lane & 15);
      const int k = ks * 32 + (lane >> 4) * 8 + j;
      const int grow = (nl >> 3) * 1024 + blk * 8 + (nl & 7);
      const float v = (k < 1024) ? Wih1[(size_t)grow * 1024 + k]
                                 : Whh1[(size_t)grow * 1024 + (k - 1024)];
      wsw1[o] = __float2bfloat16(v);
    }
  }
}

__global__ void k_small(const float* __restrict__ Wout,
                        const float* __restrict__ bih0, const float* __restrict__ bhh0,
                        const float* __restrict__ bih1, const float* __restrict__ bhh1,
                        bf16* __restrict__ woutbf, float* __restrict__ bias0,
                        float* __restrict__ bias1) {
  const int i = blockIdx.x * 256 + threadIdx.x;
  if (i < NO * NH) woutbf[i] = __float2bfloat16(Wout[i]);
  if (i < 4096) {
    bias0[i] = bih0[i] + bhh0[i];
    bias1[i] = bih1[i] + bhh1[i];
  }
}

// ---------------- persistent fused 2-layer LSTM recurrence ----------------
// grid = 256 x 256, 1 block/CU. blocks 0..127: layer0, 128..255: layer1.
// NO flags, NO arrival counters, NO producer-side drain: consumers poll the
// h data itself (sentinel-prefilled) with agent-scope loads and re-sweep
// until their exact chunks are sentinel-free. Per-step protocol collapses to
// store-propagate + one successful load sweep. Deadlock-free by induction:
// producers never wait on consumers; every chunk is unconditionally written.
__global__ __launch_bounds__(256, 1) void lstm_recur(
    const bf16* __restrict__ xbf, const bf16* __restrict__ wsw0, const bf16* __restrict__ wsw1,
    const float* __restrict__ bias0, const float* __restrict__ bias1,
    bf16* __restrict__ h1hist, bf16* __restrict__ h2hist) {
  __shared__ char Wlds[131072];
  __shared__ float red[64][33];

  const int tid = threadIdx.x;
  const int bid = blockIdx.x;
  const int layer = bid >> 7;
  const int blk = bid & 127;
  const int lane = tid & 63;
  const int wid = tid >> 6;
  const int mh = wid & 1;
  const int kh = wid >> 1;
  const int q = lane >> 4;
  const int ml = lane & 15;
  const int colbase = blk * 8;
  const int row0 = mh * 32 + ml;        // mt=0 A-row
  const int row1 = mh * 32 + 16 + ml;   // mt=1 A-row

  { // weight slice -> LDS once
    const char* src = layer ? (const char*)wsw1 + (size_t)blk * 131072
                            : (const char*)wsw0 + (size_t)blk * 98304;
    const int nb = layer ? 131072 : 98304;
    for (int off = tid * 16; off < nb; off += 256 * 16)
      *(uint4*)(Wlds + off) = *(const uint4*)(src + off);
  }

  float biasv[2];
  {
    const float* bs = layer ? bias1 : bias0;
#pragma unroll
    for (int nt = 0; nt < 2; ++nt) {
      const int nl = nt * 16 + ml;
      biasv[nt] = bs[(nl >> 3) * 1024 + colbase + (nl & 7)];
    }
  }
  __syncthreads();

  float cstate[2] = {0.f, 0.f};
  const f32x4 zacc = {0.f, 0.f, 0.f, 0.f};
  const char* WldsC = Wlds;

  for (int t = 0; t < NT_T; ++t) {
    const bf16* h1prev = h1hist + (size_t)(t - 1) * SLOT_E;  // valid iff t>0
    const bf16* h1cur  = h1hist + (size_t)t * SLOT_E;
    const bf16* h2prev = h2hist + (size_t)(t - 1) * SLOT_E;  // valid iff t>0

    f32x4 acc[2][2];
#pragma unroll
    for (int a1 = 0; a1 < 2; ++a1)
#pragma unroll
      for (int a2 = 0; a2 < 2; ++a2) acc[a1][a2] = zacc;

    if (layer == 0) {
      // x loads first (plain cached; static data; latency hides under polls)
      const bf16* xb = xbf + (size_t)t * NB * NI;
      const int kx = kh * 256 + q * 8;
      bf16x8 Ax[8][2];
      load_batch<8>(Ax, xb + (size_t)row0 * NI + kx, xb + (size_t)row1 * NI + kx);
      if (t > 0) {
        bf16x8 Ah[16][2];
        poll_tile<16>(Ah, h1prev + (size_t)row0 * NH + kh * 512 + q * 8,
                          h1prev + (size_t)row1 * NH + kh * 512 + q * 8);
        mfma_batch<8, 48>(acc, Ax, WldsC, kh * 8, lane);
        mfma_batch<16, 48>(acc, Ah, WldsC, 16 + kh * 16, lane);
      } else {
        mfma_batch<8, 48>(acc, Ax, WldsC, kh * 8, lane);
      }
    } else {
      if (kh == 0) {
        // h1[t]: L0 runs ahead -> usually first-sweep hit
        bf16x8 A0[16][2];
        poll_tile<16>(A0, h1cur + (size_t)row0 * NH + q * 8,
                          h1cur + (size_t)row1 * NH + q * 8);
        mfma_batch<16, 64>(acc, A0, WldsC, 0, lane);
        bf16x8 A1[16][2];
        poll_tile<16>(A1, h1cur + (size_t)row0 * NH + 512 + q * 8,
                          h1cur + (size_t)row1 * NH + 512 + q * 8);
        mfma_batch<16, 64>(acc, A1, WldsC, 16, lane);
      } else if (t > 0) {
        // h2[t-1]: own-layer recurrence (the binding chain)
        bf16x8 A0[16][2];
        poll_tile<16>(A0, h2prev + (size_t)row0 * NH + q * 8,
                          h2prev + (size_t)row1 * NH + q * 8);
        mfma_batch<16, 64>(acc, A0, WldsC, 32, lane);
        bf16x8 A1[16][2];
        poll_tile<16>(A1, h2prev + (size_t)row0 * NH + 512 + q * 8,
                          h2prev + (size_t)row1 * NH + 512 + q * 8);
        mfma_batch<16, 64>(acc, A1, WldsC, 48, lane);
      }
    }

    // cross-kh reduction: kh==1 publishes partials, kh==0 combines + bias.
    if (kh == 1) {
#pragma unroll
      for (int mt = 0; mt < 2; ++mt)
#pragma unroll
        for (int nt = 0; nt < 2; ++nt)
#pragma unroll
          for (int r = 0; r < 4; ++r)
            red[mh * 32 + mt * 16 + q * 4 + r][nt * 16 + ml] = acc[mt][nt][r];
    }
    __syncthreads();
    if (kh == 0) {
#pragma unroll
      for (int mt = 0; mt < 2; ++mt)
#pragma unroll
        for (int nt = 0; nt < 2; ++nt)
#pragma unroll
          for (int r = 0; r < 4; ++r) {
            const int mloc = mh * 32 + mt * 16 + q * 4 + r;
            const int nloc = nt * 16 + ml;
            red[mloc][nloc] = acc[mt][nt][r] + red[mloc][nloc] + biasv[nt];
          }
    }
    __syncthreads();

    // elementwise LSTM cell: thread owns (b = tid>>2, cc0 = (tid&3)*2, +1).
    // Packed 4B agent-scope store IS the readiness signal (never 0xFFFFFFFF:
    // h is finite, so neither bf16 half can be the NaN sentinel pattern).
    {
      const int b = tid >> 2;
      const int cc0 = (tid & 3) * 2;
      unsigned short hb[2];
#pragma unroll
      for (int e2 = 0; e2 < 2; ++e2) {
        const int cc = cc0 + e2;
        const float gi = red[b][cc];
        const float gf = red[b][8 + cc];
        const float gg = red[b][16 + cc];
        const float go = red[b][24 + cc];
        const float cn = sigm(gf) * cstate[e2] + sigm(gi) * tanh_fast(gg);
        cstate[e2] = cn;
        const float hv = sigm(go) * tanh_fast(cn);
        hb[e2] = __builtin_bit_cast(unsigned short, __float2bfloat16(hv));
      }
      const unsigned int packed = (unsigned int)hb[0] | ((unsigned int)hb[1] << 16);
      bf16* dstbase = (layer ? h2hist : h1hist) + (size_t)t * SLOT_E + (size_t)b * NH;
      __hip_atomic_store((unsigned int*)(dstbase + colbase + cc0), packed,
                         __ATOMIC_RELAXED, __HIP_MEMORY_SCOPE_AGENT);
    }

    // end-of-step barrier: protects red[] reuse across steps. (No drain/flag
    // needed for the protocol anymore -- the store above is fire-and-forget.)
    __syncthreads();
  }
}

// ---------------- output projection: h2hist(slots) @ W_out^T + b_out ----------------
__global__ __launch_bounds__(256) void gemm_out(
    const bf16* __restrict__ A, const bf16* __restrict__ B,
    const float* __restrict__ bout, float* __restrict__ out) {
  __shared__ char As[8192];
  __shared__ char Bs[8192];
  const int tid = threadIdx.x;
  const int lane = tid & 63;
  const int wid = tid >> 6;
  const int wm = wid >> 1;
  const int wn = wid & 1;
  const size_t Mbase = (size_t)blockIdx.y * 128;
  const int Nbase = blockIdx.x * 128;

  const f32x4 zacc = {0.f, 0.f, 0.f, 0.f};
  f32x4 acc[4][4];
#pragma unroll
  for (int i = 0; i < 4; ++i)
#pragma unroll
    for (int j = 0; j < 4; ++j) acc[i][j] = zacc;

  for (int kc = 0; kc < 32; ++kc) {
    const int kb = kc * 32;
#pragma unroll
    for (int e = 0; e < 2; ++e) {
      const int id = e * 256 + tid;
      const int r = id >> 2;
      const int c8 = (id & 3) * 8;
      const int dst = ((r >> 4) * 64 + (c8 >> 3) * 16 + (r & 15)) * 16;
      const size_t m = Mbase + r;
      const bf16* arow = A + (m >> 6) * SLOT_E + (size_t)(m & 63) * NH;  // slot-aware row
      *(uint4*)(As + dst) = *(const uint4*)(arow + kb + c8);
      *(uint4*)(Bs + dst) = *(const uint4*)(B + (size_t)(Nbase + r) * NH + kb + c8);
    }
    __syncthreads();
    bf16x8 af[4], bfr[4];
#pragma unroll
    for (int i = 0; i < 4; ++i) {
      af[i]  = *(const bf16x8*)(As + ((wm * 4 + i) * 64 + lane) * 16);
      bfr[i] = *(const bf16x8*)(Bs + ((wn * 4 + i) * 64 + lane) * 16);
    }
#pragma unroll
    for (int i = 0; i < 4; ++i)
#pragma unroll
      for (int j = 0; j < 4; ++j)
        acc[i][j] = __builtin_amdgcn_mfma_f32_16x16x32_bf16(af[i], bfr[j], acc[i][j], 0, 0, 0);
    __syncthreads();
  }
  const int qq = lane >> 4, ml = lane & 15;
#pragma unroll
  for (int i = 0; i < 4; ++i)
#pragma unroll
    for (int j = 0; j < 4; ++j)
#pragma unroll
      for (int r = 0; r < 4; ++r) {
        const size_t m = Mbase + wm * 64 + i * 16 + qq * 4 + r;
        const int n = Nbase + wn * 64 + j * 16 + ml;
        out[m * NO + n] = acc[i][j][r] + bout[n];
      }
}

// ---------------- host ----------------
extern "C" void kernel_launch(void* const* d_in, const int* in_sizes, int n_in,
                              void* d_out, int out_size, void* d_ws, size_t ws_size,
                              hipStream_t stream) {
  (void)in_sizes; (void)n_in; (void)out_size; (void)ws_size;
  const float* x    = (const float*)d_in[0];
  const float* Wih0 = (const float*)d_in[1];
  const float* Whh0 = (const float*)d_in[2];
  const float* bih0 = (const float*)d_in[3];
  const float* bhh0 = (const float*)d_in[4];
  const float* Wih1 = (const float*)d_in[5];
  const float* Whh1 = (const float*)d_in[6];
  const float* bih1 = (const float*)d_in[7];
  const float* bhh1 = (const float*)d_in[8];
  const float* Wout = (const float*)d_in[9];
  const float* bout = (const float*)d_in[10];
  float* out = (float*)d_out;
  char* ws = (char*)d_ws;

  bf16*  xbf    = (bf16*)(ws + OFF_XBF);
  bf16*  wsw0   = (bf16*)(ws + OFF_WSW0);
  bf16*  wsw1   = (bf16*)(ws + OFF_WSW1);
  bf16*  woutbf = (bf16*)(ws + OFF_WOUT);
  float* bias0  = (float*)(ws + OFF_B0);
  float* bias1  = (float*)(ws + OFF_B1);
  bf16*  h1hist = (bf16*)(ws + OFF_H1);
  bf16*  h2hist = (bf16*)(ws + OFF_H2);

  k_convert_x<<<8192, 256, 0, stream>>>(x, xbf);
  k_fill<<<8192, 256, 0, stream>>>((u32x4*)(ws + OFF_H1), (SZ_H1 + SZ_H2) / 16);
  k_build_wsw<<<14336, 256, 0, stream>>>(Wih0, Whh0, Wih1, Whh1, wsw0, wsw1);
  k_small<<<2048, 256, 0, stream>>>(Wout, bih0, bhh0, bih1, bhh1, woutbf, bias0, bias1);
  lstm_recur<<<256, 256, 0, stream>>>(xbf, wsw0, wsw1, bias0, bias1, h1hist, h2hist);
  gemm_out<<<dim3(4, 256), 256, 0, stream>>>(h2hist, woutbf, bout, out);
}

// Round 7
// 6190.612 us; speedup vs baseline: 2.8749x; 2.8749x over previous
//
#include <hip/hip_runtime.h>
#include <hip/hip_bf16.h>
#include <cstdint>
#include <cstddef>

typedef short bf16x8 __attribute__((ext_vector_type(8)));
typedef float f32x4  __attribute__((ext_vector_type(4)));
typedef __hip_bfloat16 bf16;

#define NT_T 512
#define NB   64
#define NI   512
#define NH   1024
#define NO   512

// h history slots: 64x1024 bf16 + 128-element pad (slot-aligned, no line straddle)
static constexpr size_t SLOT_E = (size_t)NB * NH + 128;
static constexpr size_t SLOT_B = SLOT_E * 2;

// ---------------- workspace layout (bytes, all 256-aligned) ----------------
static constexpr size_t OFF_XBF   = 0;
static constexpr size_t SZ_XBF    = (size_t)NT_T * NB * NI * 2;
static constexpr size_t OFF_WSW0  = OFF_XBF + SZ_XBF;
static constexpr size_t SZ_WSW0   = 128ull * 98304;
static constexpr size_t OFF_WSW1  = OFF_WSW0 + SZ_WSW0;
static constexpr size_t SZ_WSW1   = 128ull * 131072;
static constexpr size_t OFF_WOUT  = OFF_WSW1 + SZ_WSW1;
static constexpr size_t SZ_WOUT   = (size_t)NO * NH * 2;
static constexpr size_t OFF_B0    = OFF_WOUT + SZ_WOUT;
static constexpr size_t OFF_B1    = OFF_B0 + 4096 * 4;
static constexpr size_t OFF_H1    = OFF_B1 + 4096 * 4;
static constexpr size_t SZ_H1     = (size_t)NT_T * SLOT_B;
static constexpr size_t OFF_H2    = OFF_H1 + SZ_H1;
static constexpr size_t SZ_H2     = (size_t)NT_T * SLOT_B;
// flags[layer(2)][blk(128)][grp(4)][t(512)] ushort: producer-private lines
// (one 1KB region per (blk,grp) producer wave -> zero store serialization)
static constexpr size_t OFF_FLG   = OFF_H2 + SZ_H2;
static constexpr size_t SZ_FLG    = 2ull * 128 * 4 * 512 * 2;   // 1 MB
// total ~199.4 MB

__device__ __forceinline__ float sigm(float x) {
  return 1.0f / (1.0f + __expf(-x));
}
__device__ __forceinline__ float tanh_fast(float x) {
  x = fminf(15.0f, fmaxf(-15.0f, x));
  const float e = __expf(2.0f * x);
  return (e - 1.0f) / (e + 1.0f);
}

// Per-wave flag wait over producer-private slots (R3-proven form). Agent-scope
// loads are served fresh from the coherence point. Trailing compiler fence
// keeps subsequent cached bulk h-loads from hoisting above.
__device__ __forceinline__ void waitf2(const unsigned short* f0, const unsigned short* f1) {
  while (true) {
    const int a = __hip_atomic_load(f0, __ATOMIC_RELAXED, __HIP_MEMORY_SCOPE_AGENT);
    const int b = __hip_atomic_load(f1, __ATOMIC_RELAXED, __HIP_MEMORY_SCOPE_AGENT);
    if (__all((a != 0) && (b != 0))) break;
    __builtin_amdgcn_s_sleep(1);
  }
  asm volatile("" ::: "memory");
}

// batch load N 16B fragments (one per ks), row = lane-derived, stride 32 elems
template <int N>
__device__ __forceinline__ void load_frags(bf16x8 (&A)[N], const bf16* p) {
#pragma unroll
  for (int i = 0; i < N; ++i) A[i] = *(const bf16x8*)(p + i * 32);
}

template <int N, int KSW>
__device__ __forceinline__ void mfma_frags(f32x4 (&acc)[2], const bf16x8 (&A)[N],
                                           const char* Wlds, int ksbase, int lane) {
#pragma unroll
  for (int i = 0; i < N; ++i) {
#pragma unroll
    for (int nt = 0; nt < 2; ++nt) {
      const bf16x8 b = *(const bf16x8*)(Wlds + ((size_t)(nt * KSW + ksbase + i) * 64 + lane) * 16);
      acc[nt] = __builtin_amdgcn_mfma_f32_16x16x32_bf16(A[i], b, acc[nt], 0, 0, 0);
    }
  }
}

// ---------------- prep kernels ----------------
__global__ void k_convert_x(const float* __restrict__ x, bf16* __restrict__ xbf) {
  const size_t n = (size_t)NT_T * NB * NI;
  for (size_t i = (size_t)blockIdx.x * blockDim.x + threadIdx.x; i < n;
       i += (size_t)gridDim.x * blockDim.x)
    xbf[i] = __float2bfloat16(x[i]);
}

// Per-block, per-lane fragment-ordered weight images.
// B-fragment of mfma_f32_16x16x32_bf16: lane l holds B[n = l&15][k = (l>>4)*8 + j].
// Layout: [blk][nt(2)][ks][lane(64)][j(8)]; K-concat: L0 [W_ih0|W_hh0] ks 0..47,
// L1 [W_ih1|W_hh1] ks 0..63. Gate rows per block: [i f g o] x 8 cols at blk*8.
__global__ void k_build_wsw(const float* __restrict__ Wih0, const float* __restrict__ Whh0,
                            const float* __restrict__ Wih1, const float* __restrict__ Whh1,
                            bf16* __restrict__ wsw0, bf16* __restrict__ wsw1) {
  const size_t L0N = 128ull * 2 * 48 * 64 * 8;
  const size_t L1N = 128ull * 2 * 64 * 64 * 8;
  const size_t n = L0N + L1N;
  for (size_t i = (size_t)blockIdx.x * blockDim.x + threadIdx.x; i < n;
       i += (size_t)gridDim.x * blockDim.x) {
    if (i < L0N) {
      size_t idx = i;
      const int j = idx & 7;    idx >>= 3;
      const int lane = idx & 63; idx >>= 6;
      const int ks = (int)(idx % 48); idx /= 48;
      const int nt = idx & 1;
      const int blk = (int)(idx >> 1);
      const int nl = nt * 16 + (lane & 15);
      const int k = ks * 32 + (lane >> 4) * 8 + j;
      const int grow = (nl >> 3) * 1024 + blk * 8 + (nl & 7);
      const float v = (k < 512) ? Wih0[(size_t)grow * 512 + k]
                                : Whh0[(size_t)grow * 1024 + (k - 512)];
      wsw0[i] = __float2bfloat16(v);
    } else {
      size_t idx = i - L0N;
      const size_t o = idx;
      const int j = idx & 7;    idx >>= 3;
      const int lane = idx & 63; idx >>= 6;
      const int ks = (int)(idx % 64); idx /= 64;
      const int nt = idx & 1;
      const int blk = (int)(idx >> 1);
      const int nl = nt * 16 + (lane & 15);
      const int k = ks * 32 + (lane >> 4) * 8 + j;
      const int grow = (nl >> 3) * 1024 + blk * 8 + (nl & 7);
      const float v = (k < 1024) ? Wih1[(size_t)grow * 1024 + k]
                                 : Whh1[(size_t)grow * 1024 + (k - 1024)];
      wsw1[o] = __float2bfloat16(v);
    }
  }
}

__global__ void k_small(const float* __restrict__ Wout,
                        const float* __restrict__ bih0, const float* __restrict__ bhh0,
                        const float* __restrict__ bih1, const float* __restrict__ bhh1,
                        bf16* __restrict__ woutbf, float* __restrict__ bias0,
                        float* __restrict__ bias1, unsigned int* __restrict__ flg) {
  const int i = blockIdx.x * 256 + threadIdx.x;
  if (i < NO * NH) woutbf[i] = __float2bfloat16(Wout[i]);
  if (i < 4096) {
    bias0[i] = bih0[i] + bhh0[i];
    bias1[i] = bih1[i] + bhh1[i];
  }
  if (i < (int)(SZ_FLG / 4)) flg[i] = 0u;  // zero the flag region
}

// ---------------- persistent fused 2-layer LSTM recurrence ----------------
// grid = 256 x 512thr (8 waves). blocks 0..127: layer0, 128..255: layer1.
// ROW-GROUP decomposition: 4 independent groups of 16 batch rows, 2 waves
// each (kh = k-half). ZERO __syncthreads in the step loop:
//  - kh=1 wave: waits the on-chain h flags (h1[t-1] for L0 / h2[t-1] for L1),
//    loads 32 fragments, 64 MFMAs, publishes partial gates to a double-
//    buffered LDS patch + LDS flag (intra-CU handshake, ~0.1us).
//  - kh=0 wave: off-chain part (x for L0 / pre-satisfied h1[t] for L1),
//    combines partials + bias, computes the LSTM cell for its 16 rows IN-WAVE
//    (via a small LDS redistribution), stores h (packed 4B agent stores),
//    waits ITS OWN vmcnt(0) (wave-scope, not block), sets the per-(blk,grp)
//    global flag.
// Consumers poll only their row-group's 128 producer flags (2 per lane).
// Per-wave fragment count drops to <=32 -> fewer serialized miss epochs.
__global__ __launch_bounds__(512, 1) void lstm_recur(
    const bf16* __restrict__ xbf, const bf16* __restrict__ wsw0, const bf16* __restrict__ wsw1,
    const float* __restrict__ bias0, const float* __restrict__ bias1,
    bf16* __restrict__ h1hist, bf16* __restrict__ h2hist, unsigned short* __restrict__ flg) {
  __shared__ char Wlds[131072];
  __shared__ float grpP[2][4][2][16][16];  // [buf t&1][g][nt][row16][col16] partials
  __shared__ float grpG[4][16][33];        // combined gates per group (padded)
  __shared__ int grpFlag[4][16];           // [g][0] = t+1 when partials ready

  const int tid = threadIdx.x;
  const int bid = blockIdx.x;
  const int layer = bid >> 7;
  const int blk = bid & 127;
  const int lane = tid & 63;
  const int wid = tid >> 6;
  const int g = wid >> 1;        // row-group: batch rows 16g..16g+15
  const int kh = wid & 1;        // k-half / role
  const int q = lane >> 4;
  const int ml = lane & 15;
  const int colbase = blk * 8;
  const int rb = g * 16;

  { // weight slice -> LDS once
    const char* src = layer ? (const char*)wsw1 + (size_t)blk * 131072
                            : (const char*)wsw0 + (size_t)blk * 98304;
    const int nb = layer ? 131072 : 98304;
    for (int off = tid * 16; off < nb; off += 512 * 16)
      *(uint4*)(Wlds + off) = *(const uint4*)(src + off);
  }

  float biasv[2];
  {
    const float* bs = layer ? bias1 : bias0;
#pragma unroll
    for (int nt = 0; nt < 2; ++nt) {
      const int nl = nt * 16 + ml;
      biasv[nt] = bs[(nl >> 3) * 1024 + colbase + (nl & 7)];
    }
  }
  if (tid < 64) ((int*)grpFlag)[tid] = 0;
  __syncthreads();  // one-time: W + grpFlag ready

  const int KS = layer ? 64 : 48;
  float cstate[2] = {0.f, 0.f};
  const f32x4 zacc = {0.f, 0.f, 0.f, 0.f};
  const char* WldsC = Wlds;

  const unsigned short* f_l0 = flg;                            // h1 producers
  const unsigned short* f_l1 = flg + (size_t)128 * 4 * 512;    // h2 producers
  unsigned short* fme = flg + ((((size_t)layer * 128 + blk) * 4 + g) << 9);

  for (int t = 0; t < NT_T; ++t) {
    const bf16* h1prev = h1hist + (size_t)(t - 1) * SLOT_E;  // valid iff t>0
    const bf16* h1cur  = h1hist + (size_t)t * SLOT_E;
    const bf16* h2prev = h2hist + (size_t)(t - 1) * SLOT_E;  // valid iff t>0

    f32x4 acc[2];
    acc[0] = zacc; acc[1] = zacc;

    if (layer == 0) {
      if (kh == 0) {
        // x-part: fully off-chain, starts immediately
        const bf16* xb = xbf + (size_t)t * NB * NI + (size_t)(rb + ml) * NI + q * 8;
        bf16x8 Ax[16];
        load_frags<16>(Ax, xb);
        __builtin_amdgcn_sched_barrier(0);
        mfma_frags<16, 48>(acc, Ax, WldsC, 0, lane);
      } else if (t > 0) {
        // on-chain: h1[t-1], rows of this group only
        waitf2(f_l0 + (((size_t)lane * 4 + g) << 9) + (t - 1),
               f_l0 + (((size_t)(64 + lane) * 4 + g) << 9) + (t - 1));
        const bf16* hb = h1prev + (size_t)(rb + ml) * NH + q * 8;
        bf16x8 Ah[32];
        load_frags<32>(Ah, hb);
        __builtin_amdgcn_sched_barrier(0);
        mfma_frags<32, 48>(acc, Ah, WldsC, 16, lane);
      }
    } else {
      if (kh == 0) {
        // h1[t]: L0 runs ahead -> usually pre-satisfied
        waitf2(f_l0 + (((size_t)lane * 4 + g) << 9) + t,
               f_l0 + (((size_t)(64 + lane) * 4 + g) << 9) + t);
        const bf16* hb = h1cur + (size_t)(rb + ml) * NH + q * 8;
        bf16x8 Ah[32];
        load_frags<32>(Ah, hb);
        __builtin_amdgcn_sched_barrier(0);
        mfma_frags<32, 64>(acc, Ah, WldsC, 0, lane);
      } else if (t > 0) {
        // on-chain: h2[t-1]
        waitf2(f_l1 + (((size_t)lane * 4 + g) << 9) + (t - 1),
               f_l1 + (((size_t)(64 + lane) * 4 + g) << 9) + (t - 1));
        const bf16* hb = h2prev + (size_t)(rb + ml) * NH + q * 8;
        bf16x8 Ah[32];
        load_frags<32>(Ah, hb);
        __builtin_amdgcn_sched_barrier(0);
        mfma_frags<32, 64>(acc, Ah, WldsC, 32, lane);
      }
    }

    if (kh == 1) {
      // publish partials to the double-buffered LDS patch + LDS flag.
      // Double-buffer safety: overwrite of buf p at step t requires the global
      // flag of step t-1, which implies the combiner finished step t-1 --
      // hence finished READING buf p at step t-2. No back-handshake needed.
#pragma unroll
      for (int nt = 0; nt < 2; ++nt)
#pragma unroll
        for (int r = 0; r < 4; ++r)
          grpP[t & 1][g][nt][q * 4 + r][ml] = acc[nt][r];
      asm volatile("s_waitcnt lgkmcnt(0)" ::: "memory");
      __hip_atomic_store(&grpFlag[g][0], t + 1, __ATOMIC_RELAXED, __HIP_MEMORY_SCOPE_WORKGROUP);
    } else {
      // combine partner partials + bias
      while (__hip_atomic_load(&grpFlag[g][0], __ATOMIC_RELAXED,
                               __HIP_MEMORY_SCOPE_WORKGROUP) < t + 1) {}
      asm volatile("" ::: "memory");
#pragma unroll
      for (int nt = 0; nt < 2; ++nt)
#pragma unroll
        for (int r = 0; r < 4; ++r)
          grpG[g][q * 4 + r][nt * 16 + ml] =
              acc[nt][r] + grpP[t & 1][g][nt][q * 4 + r][ml] + biasv[nt];
      asm volatile("s_waitcnt lgkmcnt(0)" ::: "memory");

      // LSTM cell for this group's 16 rows, in-wave: lane -> (row=lane>>2,
      // cols (lane&3)*2 + {0,1}) -> packed 4B agent store
      const int b16 = lane >> 2;
      const int cc0 = (lane & 3) * 2;
      unsigned short hb2[2];
#pragma unroll
      for (int e2 = 0; e2 < 2; ++e2) {
        const int cc = cc0 + e2;
        const float gi = grpG[g][b16][cc];
        const float gf = grpG[g][b16][8 + cc];
        const float gg = grpG[g][b16][16 + cc];
        const float go = grpG[g][b16][24 + cc];
        const float cn = sigm(gf) * cstate[e2] + sigm(gi) * tanh_fast(gg);
        cstate[e2] = cn;
        const float hv = sigm(go) * tanh_fast(cn);
        hb2[e2] = __builtin_bit_cast(unsigned short, __float2bfloat16(hv));
      }
      const unsigned int packed = (unsigned int)hb2[0] | ((unsigned int)hb2[1] << 16);
      bf16* dstbase = (layer ? h2hist : h1hist) + (size_t)t * SLOT_E
                      + (size_t)(rb + b16) * NH;
      __hip_atomic_store((unsigned int*)(dstbase + colbase + cc0), packed,
                         __ATOMIC_RELAXED, __HIP_MEMORY_SCOPE_AGENT);

      // wave-scope publish: own stores acked at the coherence point, then the
      // producer-private flag (fire-and-forget). No block barrier involved.
      asm volatile("s_waitcnt vmcnt(0)" ::: "memory");
      if (lane == 0)
        __hip_atomic_store(fme + t, (unsigned short)1,
                           __ATOMIC_RELAXED, __HIP_MEMORY_SCOPE_AGENT);
    }
  }
}

// ---------------- output projection: h2hist(slots) @ W_out^T + b_out ----------------
__global__ __launch_bounds__(256) void gemm_out(
    const bf16* __restrict__ A, const bf16* __restrict__ B,
    const float* __restrict__ bout, float* __restrict__ out) {
  __shared__ char As[8192];
  __shared__ char Bs[8192];
  const int tid = threadIdx.x;
  const int lane = tid & 63;
  const int wid = tid >> 6;
  const int wm = wid >> 1;
  const int wn = wid & 1;
  const size_t Mbase = (size_t)blockIdx.y * 128;
  const int Nbase = blockIdx.x * 128;

  const f32x4 zacc = {0.f, 0.f, 0.f, 0.f};
  f32x4 acc[4][4];
#pragma unroll
  for (int i = 0; i < 4; ++i)
#pragma unroll
    for (int j = 0; j < 4; ++j) acc[i][j] = zacc;

  for (int kc = 0; kc < 32; ++kc) {
    const int kb = kc * 32;
#pragma unroll
    for (int e = 0; e < 2; ++e) {
      const int id = e * 256 + tid;
      const int r = id >> 2;
      const int c8 = (id & 3) * 8;
      const int dst = ((r >> 4) * 64 + (c8 >> 3) * 16 + (r & 15)) * 16;
      const size_t m = Mbase + r;
      const bf16* arow = A + (m >> 6) * SLOT_E + (size_t)(m & 63) * NH;  // slot-aware row
      *(uint4*)(As + dst) = *(const uint4*)(arow + kb + c8);
      *(uint4*)(Bs + dst) = *(const uint4*)(B + (size_t)(Nbase + r) * NH + kb + c8);
    }
    __syncthreads();
    bf16x8 af[4], bfr[4];
#pragma unroll
    for (int i = 0; i < 4; ++i) {
      af[i]  = *(const bf16x8*)(As + ((wm * 4 + i) * 64 + lane) * 16);
      bfr[i] = *(const bf16x8*)(Bs + ((wn * 4 + i) * 64 + lane) * 16);
    }
#pragma unroll
    for (int i = 0; i < 4; ++i)
#pragma unroll
      for (int j = 0; j < 4; ++j)
        acc[i][j] = __builtin_amdgcn_mfma_f32_16x16x32_bf16(af[i], bfr[j], acc[i][j], 0, 0, 0);
    __syncthreads();
  }
  const int qq = lane >> 4, ml = lane & 15;
#pragma unroll
  for (int i = 0; i < 4; ++i)
#pragma unroll
    for (int j = 0; j < 4; ++j)
#pragma unroll
      for (int r = 0; r < 4; ++r) {
        const size_t m = Mbase + wm * 64 + i * 16 + qq * 4 + r;
        const int n = Nbase + wn * 64 + j * 16 + ml;
        out[m * NO + n] = acc[i][j][r] + bout[n];
      }
}

// ---------------- host ----------------
extern "C" void kernel_launch(void* const* d_in, const int* in_sizes, int n_in,
                              void* d_out, int out_size, void* d_ws, size_t ws_size,
                              hipStream_t stream) {
  (void)in_sizes; (void)n_in; (void)out_size; (void)ws_size;
  const float* x    = (const float*)d_in[0];
  const float* Wih0 = (const float*)d_in[1];
  const float* Whh0 = (const float*)d_in[2];
  const float* bih0 = (const float*)d_in[3];
  const float* bhh0 = (const float*)d_in[4];
  const float* Wih1 = (const float*)d_in[5];
  const float* Whh1 = (const float*)d_in[6];
  const float* bih1 = (const float*)d_in[7];
  const float* bhh1 = (const float*)d_in[8];
  const float* Wout = (const float*)d_in[9];
  const float* bout = (const float*)d_in[10];
  float* out = (float*)d_out;
  char* ws = (char*)d_ws;

  bf16*  xbf    = (bf16*)(ws + OFF_XBF);
  bf16*  wsw0   = (bf16*)(ws + OFF_WSW0);
  bf16*  wsw1   = (bf16*)(ws + OFF_WSW1);
  bf16*  woutbf = (bf16*)(ws + OFF_WOUT);
  float* bias0  = (float*)(ws + OFF_B0);
  float* bias1  = (float*)(ws + OFF_B1);
  bf16*  h1hist = (bf16*)(ws + OFF_H1);
  bf16*  h2hist = (bf16*)(ws + OFF_H2);
  unsigned short* flg = (unsigned short*)(ws + OFF_FLG);

  k_convert_x<<<8192, 256, 0, stream>>>(x, xbf);
  k_build_wsw<<<14336, 256, 0, stream>>>(Wih0, Whh0, Wih1, Whh1, wsw0, wsw1);
  k_small<<<2048, 256, 0, stream>>>(Wout, bih0, bhh0, bih1, bhh1, woutbf, bias0, bias1,
                                    (unsigned int*)flg);
  lstm_recur<<<256, 512, 0, stream>>>(xbf, wsw0, wsw1, bias0, bias1, h1hist, h2hist, flg);
  gemm_out<<<dim3(4, 256), 256, 0, stream>>>(h2hist, woutbf, bout, out);
}